// Round 11
// baseline (402.662 us; speedup 1.0000x reference)
//
#include <hip/hip_runtime.h>
#include <math.h>

#define N 8192
#define D 512
#define KSEL 5
#define TEMP_INV 10.0f
#define CCAP 64
#define BK 64
#define CPITCH 136  // epilogue C-stage pitch in shorts (R5-proven)
#define NSTRIP 128  // 64-col strips per row
#define NTILE 64
#define NBLK (NTILE * (NTILE + 1) / 2)  // 2080 upper-triangle tiles

using short8 = __attribute__((ext_vector_type(8))) short;
using floatx4 = __attribute__((ext_vector_type(4))) float;

__device__ inline unsigned short f2b(float f) {  // fp32 -> bf16 RNE (monotone)
    unsigned int u = __float_as_uint(f);
    unsigned int r = (u + 0x7FFFu + ((u >> 16) & 1u)) >> 16;
    return (unsigned short)r;
}
__device__ inline float b2f(unsigned short u) {
    return __uint_as_float(((unsigned int)u) << 16);
}

// pack (bf16 value, col) into one sortable u32: val desc, then idx asc.
// high 16 = bf16 mapped monotone-to-unsigned, low 13 = 8191-col.
__device__ inline unsigned int packvi(unsigned short b, int col) {
    const unsigned short s =
        (b & 0x8000) ? (unsigned short)(~b) : (unsigned short)(b | 0x8000);
    return ((unsigned int)s << 13) | (unsigned int)(8191 - col);
}
__device__ inline float upackval(unsigned int key) {
    const unsigned short s = (unsigned short)(key >> 13);
    const unsigned short b =
        (s & 0x8000) ? (unsigned short)(s & 0x7FFF) : (unsigned short)(~s);
    return b2f(b);
}

__device__ inline void gload_lds16(const unsigned short* g, unsigned short* l) {
    __builtin_amdgcn_global_load_lds((__attribute__((address_space(1))) void*)g,
                                     (__attribute__((address_space(3))) void*)l, 16, 0, 0);
}

// ---------------- Kernel 1: norms + bf16 normalized rows -----------------
__global__ __launch_bounds__(64) void prep_kernel(const float* __restrict__ X,
                                                  unsigned short* __restrict__ Xb) {
    const int row = blockIdx.x;
    const int t = threadIdx.x;
    const float4* xr = (const float4*)(X + (size_t)row * D);
    const float4 a = xr[t];
    const float4 b = xr[t + 64];
    float ss = a.x * a.x + a.y * a.y + a.z * a.z + a.w * a.w +
               b.x * b.x + b.y * b.y + b.z * b.z + b.w * b.w;
#pragma unroll
    for (int off = 32; off > 0; off >>= 1) ss += __shfl_xor(ss, off, 64);
    const float iv = 1.0f / fmaxf(sqrtf(ss), 1e-12f);
    ushort4 ua, ub;
    ua.x = f2b(a.x * iv); ua.y = f2b(a.y * iv); ua.z = f2b(a.z * iv); ua.w = f2b(a.w * iv);
    ub.x = f2b(b.x * iv); ub.y = f2b(b.y * iv); ub.z = f2b(b.z * iv); ub.w = f2b(b.w * iv);
    ((ushort4*)(Xb + (size_t)row * D))[t] = ua;
    ((ushort4*)(Xb + (size_t)row * D))[t + 64] = ub;
}

// ---------------- Kernel 2: symmetric bf16 MFMA GEMM ---------------------
// R10-proven (mirror write deleted; scanfin reads transposed locations).
// R11: UNCHANGED CODE — but launched TWICE this round as a timing
// instrument: gemm is idempotent, so dur_delta vs R10 = standalone gemm
// time, independent of what else sits in the timed window.
__global__ __launch_bounds__(256) void gemm_kernel(const unsigned short* __restrict__ Xb,
                                                   unsigned short* __restrict__ Cout,
                                                   unsigned short* __restrict__ rowmaxG) {
    __shared__ unsigned short smem[128 * CPITCH];  // 34.8 KB (A|B 32 KB, then Cs)
    unsigned short* Asm = smem;
    unsigned short* Bsm = smem + 8192;
    const int tid = threadIdx.x;
    const int w = tid >> 6;
    const int lane = tid & 63;
    const int wr = w >> 1, wc = w & 1;

    // decode upper-triangle pair: off(ti) = ti*(129-ti)/2
    const int t = (int)blockIdx.x;
    int tib = (int)((129.0 - sqrt(129.0 * 129.0 - 8.0 * (double)t)) * 0.5);
    while ((tib + 1) * (129 - (tib + 1)) / 2 <= t) ++tib;
    while (tib * (129 - tib) / 2 > t) --tib;
    const int tjb = tib + (t - tib * (129 - tib) / 2);
    const int i0 = tib * 128, j0 = tjb * 128;

    floatx4 acc[4][4];
#pragma unroll
    for (int ti = 0; ti < 4; ++ti)
#pragma unroll
        for (int tj = 0; tj < 4; ++tj) acc[ti][tj] = (floatx4){0.f, 0.f, 0.f, 0.f};

    const unsigned short* gA[4];
    const unsigned short* gB[4];
    unsigned short* lA[4];
    unsigned short* lB[4];
#pragma unroll
    for (int p = 0; p < 4; ++p) {
        const int slot = p * 256 + tid;
        const int row = slot >> 3;
        const int kq = (slot & 7) ^ (row & 7);
        gA[p] = Xb + (size_t)(i0 + row) * D + kq * 8;
        gB[p] = Xb + (size_t)(j0 + row) * D + kq * 8;
        lA[p] = Asm + slot * 8;
        lB[p] = Bsm + slot * 8;
    }

    const int r = lane & 15;
    const int q = lane >> 4;
    const int aRow0 = wr * 64 + r;
    const int bRow0 = wc * 64 + r;
    const int rx = r & 7;

#pragma unroll
    for (int p = 0; p < 4; ++p) {
        gload_lds16(gA[p], lA[p]);
        gload_lds16(gB[p], lB[p]);
    }

    for (int kc = 0; kc < D / BK; ++kc) {
        __syncthreads();
        short8 af[2][4], bf[2][4];
#pragma unroll
        for (int tt = 0; tt < 2; ++tt)
#pragma unroll
            for (int ti = 0; ti < 4; ++ti) {
                af[tt][ti] = *(const short8*)(Asm +
                    ((aRow0 + ti * 16) * 8 + ((tt * 4 + q) ^ rx)) * 8);
                bf[tt][ti] = *(const short8*)(Bsm +
                    ((bRow0 + ti * 16) * 8 + ((tt * 4 + q) ^ rx)) * 8);
            }
        __syncthreads();
        if (kc < D / BK - 1) {
            const int o = (kc + 1) * BK;
#pragma unroll
            for (int p = 0; p < 4; ++p) {
                gload_lds16(gA[p] + o, lA[p]);
                gload_lds16(gB[p] + o, lB[p]);
            }
        }
#pragma unroll
        for (int tt = 0; tt < 2; ++tt)
#pragma unroll
            for (int ti = 0; ti < 4; ++ti)
#pragma unroll
                for (int tj = 0; tj < 4; ++tj)
                    acc[ti][tj] = __builtin_amdgcn_mfma_f32_16x16x32_bf16(
                        af[tt][ti], bf[tt][tj], acc[ti][tj], 0, 0, 0);
    }

    // ---- A-side strip maxima: rows i0.., strip tjb*2 + wc ----
    {
        float rmax[16];
#pragma unroll
        for (int ti = 0; ti < 4; ++ti)
#pragma unroll
            for (int reg = 0; reg < 4; ++reg) {
                const float m0 = fmaxf(acc[ti][0][reg], acc[ti][1][reg]);
                const float m1 = fmaxf(acc[ti][2][reg], acc[ti][3][reg]);
                rmax[ti * 4 + reg] = fmaxf(m0, m1);
            }
#pragma unroll
        for (int k = 0; k < 16; ++k)
#pragma unroll
            for (int m = 1; m < 16; m <<= 1)
                rmax[k] = fmaxf(rmax[k], __shfl_xor(rmax[k], m, 64));
        if (r == 0) {
            const int strip = tjb * 2 + wc;
#pragma unroll
            for (int ti = 0; ti < 4; ++ti)
#pragma unroll
                for (int reg = 0; reg < 4; ++reg)
                    rowmaxG[(size_t)(i0 + wr * 64 + ti * 16 + q * 4 + reg) * NSTRIP +
                            strip] = f2b(rmax[ti * 4 + reg]);
        }
    }

    // ---- B-side strip maxima (mirror rows): rows j0.., strip tib*2 + wr --
    if (tib != tjb) {
        float cmax[4];
#pragma unroll
        for (int tj = 0; tj < 4; ++tj) {
            float m = -1e30f;
#pragma unroll
            for (int ti = 0; ti < 4; ++ti)
#pragma unroll
                for (int reg = 0; reg < 4; ++reg) m = fmaxf(m, acc[ti][tj][reg]);
            m = fmaxf(m, __shfl_xor(m, 16, 64));
            m = fmaxf(m, __shfl_xor(m, 32, 64));
            cmax[tj] = m;
        }
        if (q == 0) {
#pragma unroll
            for (int tj = 0; tj < 4; ++tj)
                rowmaxG[(size_t)(j0 + wc * 64 + tj * 16 + r) * NSTRIP + tib * 2 + wr] =
                    f2b(cmax[tj]);
        }
    }

    // ---- epilogue: LDS restage -> coalesced bf16 C writes (direct only) --
    __syncthreads();
    unsigned short* Cs = smem;
#pragma unroll
    for (int ti = 0; ti < 4; ++ti)
#pragma unroll
        for (int tj = 0; tj < 4; ++tj)
#pragma unroll
            for (int reg = 0; reg < 4; ++reg) {
                const int rowl = wr * 64 + ti * 16 + q * 4 + reg;
                const int coll = wc * 64 + tj * 16 + r;
                Cs[rowl * CPITCH + (coll ^ ((rowl & 7) << 3))] = f2b(acc[ti][tj][reg]);
            }
    __syncthreads();
#pragma unroll
    for (int p = 0; p < 8; ++p) {
        const int id = p * 256 + tid;
        const int rw = id >> 4;
        const int c = id & 15;
        const int cc = c ^ (rw & 7);
        const int4 v = *(const int4*)&Cs[rw * CPITCH + cc * 8];
        *(int4*)&Cout[(size_t)(i0 + rw) * N + j0 + c * 8] = v;
    }
    // (mirror tile write deleted — scanfin reads the transposed locations)
}

// ---------------- Kernel 3: bf16-direct top-5 + softmax + out ------------
// R10-proven: direct strips read coalesced; left-of-diagonal strips read
// transposed locations C[col][row]. Selection/softmax R7-proven.
__global__ __launch_bounds__(256) void scanfin_kernel(const unsigned short* __restrict__ C,
                                                      const unsigned short* __restrict__ rowmaxG,
                                                      float* __restrict__ out) {
    __shared__ int acnt[4];
    __shared__ int alist[4][NSTRIP];
    __shared__ int scnt[4];
    __shared__ unsigned int sci[4][CCAP];  // packed (sortable-bf16<<13 | 8191-col)
    const int tid = threadIdx.x;
    const int w = tid >> 6;
    const int lane = tid & 63;
    const int row = (int)blockIdx.x * 4 + w;
    const unsigned short* cr = C + (size_t)row * N;
    if (lane == 0) { acnt[w] = 0; scnt[w] = 0; }

    const ushort2 su = *(const ushort2*)(rowmaxG + (size_t)row * NSTRIP + lane * 2);
    const float s0v = b2f(su.x), s1v = b2f(su.y);

    // 5th-largest strip max via knockout (proven)
    float a = s0v, b = s1v;
    float m5 = -1e30f;
#pragma unroll
    for (int s = 0; s < 5; ++s) {
        float mx = fmaxf(a, b);
#pragma unroll
        for (int m = 32; m > 0; m >>= 1) mx = fmaxf(mx, __shfl_xor(mx, m, 64));
        m5 = mx;
        const unsigned long long msk = __ballot(a == mx || b == mx);
        const int first = __ffsll(msk) - 1;
        if (lane == first) {
            if (a == mx) a = -1e30f;
            else b = -1e30f;
        }
    }
    const float thr = m5;

    if (s0v >= thr) { const int p = atomicAdd(&acnt[w], 1); alist[w][p] = lane * 2; }
    if (s1v >= thr) { const int p = atomicAdd(&acnt[w], 1); alist[w][p] = lane * 2 + 1; }
    const int na = acnt[w];

    // gather candidates from qualifying strips; one strip per round.
    const int rowtile = row >> 7;
    for (int g = 0; g < na; ++g) {
        const int s = alist[w][g];
        const int col = s * 64 + lane;
        unsigned short uv;
        if ((s >> 1) >= rowtile) {
            uv = cr[col];
        } else {
            uv = C[(size_t)col * N + row];
        }
        const float v = b2f(uv);
        if (v >= thr) {
            const int p = atomicAdd(&scnt[w], 1);
            if (p < CCAP) sci[w][p] = packvi(uv, col);
        }
    }
    int nc = scnt[w];
    if (nc > CCAP) nc = CCAP;

    // uniform serial top-5 over packed keys (distinct; val desc, idx asc)
    unsigned int t5[5] = {0u, 0u, 0u, 0u, 0u};
    for (int c = 0; c < nc; ++c) {
        const unsigned int k = sci[w][c];
        if (k > t5[4]) {
            const bool b0 = k > t5[0];
            const bool b1 = k > t5[1];
            const bool b2 = k > t5[2];
            const bool b3 = k > t5[3];
            t5[4] = b3 ? t5[3] : k;
            t5[3] = b2 ? t5[2] : (b3 ? k : t5[3]);
            t5[2] = b1 ? t5[1] : (b2 ? k : t5[2]);
            t5[1] = b0 ? t5[0] : (b1 ? k : t5[1]);
            t5[0] = b0 ? k : t5[0];
        }
    }

    // write 5 entries (out pre-zeroed by harness memset)
    if (lane == 0) {
        const float vmax = upackval(t5[0]);
        float e[KSEL];
        int ix[KSEL];
        float sum = 0.f;
#pragma unroll
        for (int s = 0; s < KSEL; ++s) {
            const bool valid = (t5[s] != 0u);
            e[s] = valid ? expf((upackval(t5[s]) - vmax) * TEMP_INV) : 0.f;
            ix[s] = valid ? (8191 - (int)(t5[s] & 8191u)) : -1;
            sum += e[s];
        }
        const float invs = 1.0f / sum;
#pragma unroll
        for (int s = 0; s < KSEL; ++s) {
            if (ix[s] >= 0) out[(size_t)row * N + ix[s]] = e[s] * invs;
        }
    }
}

extern "C" void kernel_launch(void* const* d_in, const int* in_sizes, int n_in,
                              void* d_out, int out_size, void* d_ws, size_t ws_size,
                              hipStream_t stream) {
    const float* X = (const float*)d_in[0];
    float* out = (float*)d_out;
    // ws (1 GiB): Xb bf16 [8 MB] | rowmax bf16 [2 MB] | C bf16 [128 MB @ +16 MB]
    unsigned short* Xb = (unsigned short*)d_ws;
    unsigned short* rowmaxG = (unsigned short*)(Xb + (size_t)N * D);
    unsigned short* C = (unsigned short*)((char*)d_ws + (16u << 20));

    hipLaunchKernelGGL(prep_kernel, dim3(N), dim3(64), 0, stream, X, Xb);
    // R11 INSTRUMENT: gemm launched twice (idempotent). dur_us delta vs
    // R10's 338.8 = standalone (warm) gemm time. Next round reverts to a
    // single launch and acts on the measured split.
    hipLaunchKernelGGL(gemm_kernel, dim3(NBLK), dim3(256), 0, stream, Xb, C, rowmaxG);
    hipLaunchKernelGGL(gemm_kernel, dim3(NBLK), dim3(256), 0, stream, Xb, C, rowmaxG);
    hipLaunchKernelGGL(scanfin_kernel, dim3(N / 4), dim3(256), 0, stream, C, rowmaxG, out);
}

// Round 13
// 337.521 us; speedup vs baseline: 1.1930x; 1.1930x over previous
//
#include <hip/hip_runtime.h>
#include <math.h>

#define N 8192
#define D 512
#define KSEL 5
#define TEMP_INV 10.0f
#define CCAP 64
#define BK 64
#define CPITCH 136  // epilogue C-stage pitch in shorts (R5-proven)
#define NSTRIP 128  // 64-col strips per row
#define NTILE 64
#define NBLK (NTILE * (NTILE + 1) / 2)  // 2080 upper-triangle tiles (= 8*260)

using short8 = __attribute__((ext_vector_type(8))) short;
using floatx4 = __attribute__((ext_vector_type(4))) float;

__device__ inline unsigned short f2b(float f) {  // fp32 -> bf16 RNE (monotone)
    unsigned int u = __float_as_uint(f);
    unsigned int r = (u + 0x7FFFu + ((u >> 16) & 1u)) >> 16;
    return (unsigned short)r;
}
__device__ inline float b2f(unsigned short u) {
    return __uint_as_float(((unsigned int)u) << 16);
}

// pack (bf16 value, col) into one sortable u32: val desc, then idx asc.
// high 16 = bf16 mapped monotone-to-unsigned, low 13 = 8191-col.
__device__ inline unsigned int packvi(unsigned short b, int col) {
    const unsigned short s =
        (b & 0x8000) ? (unsigned short)(~b) : (unsigned short)(b | 0x8000);
    return ((unsigned int)s << 13) | (unsigned int)(8191 - col);
}
__device__ inline float upackval(unsigned int key) {
    const unsigned short s = (unsigned short)(key >> 13);
    const unsigned short b =
        (s & 0x8000) ? (unsigned short)(s & 0x7FFF) : (unsigned short)(~s);
    return b2f(b);
}

__device__ inline void gload_lds16(const unsigned short* g, unsigned short* l) {
    __builtin_amdgcn_global_load_lds((__attribute__((address_space(1))) void*)g,
                                     (__attribute__((address_space(3))) void*)l, 16, 0, 0);
}

// ---------------- Kernel 1: norms + bf16 normalized rows -----------------
__global__ __launch_bounds__(64) void prep_kernel(const float* __restrict__ X,
                                                  unsigned short* __restrict__ Xb) {
    const int row = blockIdx.x;
    const int t = threadIdx.x;
    const float4* xr = (const float4*)(X + (size_t)row * D);
    const float4 a = xr[t];
    const float4 b = xr[t + 64];
    float ss = a.x * a.x + a.y * a.y + a.z * a.z + a.w * a.w +
               b.x * b.x + b.y * b.y + b.z * b.z + b.w * b.w;
#pragma unroll
    for (int off = 32; off > 0; off >>= 1) ss += __shfl_xor(ss, off, 64);
    const float iv = 1.0f / fmaxf(sqrtf(ss), 1e-12f);
    ushort4 ua, ub;
    ua.x = f2b(a.x * iv); ua.y = f2b(a.y * iv); ua.z = f2b(a.z * iv); ua.w = f2b(a.w * iv);
    ub.x = f2b(b.x * iv); ub.y = f2b(b.y * iv); ub.z = f2b(b.z * iv); ub.w = f2b(b.w * iv);
    ((ushort4*)(Xb + (size_t)row * D))[t] = ua;
    ((ushort4*)(Xb + (size_t)row * D))[t + 64] = ub;
}

// ---------------- Kernel 2: symmetric bf16 MFMA GEMM ---------------------
// R10-proven body. R12/R13: XCD-aware bijective block swizzle (T1). R11's
// double-launch measured gemm at ~64 us standalone — L3-BW-bound on Xb
// staging (533 MB aggregate; Xb 8 MB > 4 MB per-XCD L2, and consecutive
// blockIdx — which share the A panel — round-robin across XCDs). Chunked
// remap t = (raw%8)*260 + raw/8 (2080 = 8*260, bijective) gives each XCD
// 260 consecutive tiles -> A-panels become L2-resident per XCD.
// (R12 bench was an infra failure — container flake, same signature as R4;
// kernel re-audited sound and resubmitted unchanged.)
__global__ __launch_bounds__(256) void gemm_kernel(const unsigned short* __restrict__ Xb,
                                                   unsigned short* __restrict__ Cout,
                                                   unsigned short* __restrict__ rowmaxG) {
    __shared__ unsigned short smem[128 * CPITCH];  // 34.8 KB (A|B 32 KB, then Cs)
    unsigned short* Asm = smem;
    unsigned short* Bsm = smem + 8192;
    const int tid = threadIdx.x;
    const int w = tid >> 6;
    const int lane = tid & 63;
    const int wr = w >> 1, wc = w & 1;

    // XCD swizzle: same-XCD blocks get consecutive logical tiles
    const int traw = (int)blockIdx.x;
    const int t = (traw & 7) * (NBLK / 8) + (traw >> 3);

    // decode upper-triangle pair: off(ti) = ti*(129-ti)/2
    int tib = (int)((129.0 - sqrt(129.0 * 129.0 - 8.0 * (double)t)) * 0.5);
    while ((tib + 1) * (129 - (tib + 1)) / 2 <= t) ++tib;
    while (tib * (129 - tib) / 2 > t) --tib;
    const int tjb = tib + (t - tib * (129 - tib) / 2);
    const int i0 = tib * 128, j0 = tjb * 128;

    floatx4 acc[4][4];
#pragma unroll
    for (int ti = 0; ti < 4; ++ti)
#pragma unroll
        for (int tj = 0; tj < 4; ++tj) acc[ti][tj] = (floatx4){0.f, 0.f, 0.f, 0.f};

    const unsigned short* gA[4];
    const unsigned short* gB[4];
    unsigned short* lA[4];
    unsigned short* lB[4];
#pragma unroll
    for (int p = 0; p < 4; ++p) {
        const int slot = p * 256 + tid;
        const int row = slot >> 3;
        const int kq = (slot & 7) ^ (row & 7);
        gA[p] = Xb + (size_t)(i0 + row) * D + kq * 8;
        gB[p] = Xb + (size_t)(j0 + row) * D + kq * 8;
        lA[p] = Asm + slot * 8;
        lB[p] = Bsm + slot * 8;
    }

    const int r = lane & 15;
    const int q = lane >> 4;
    const int aRow0 = wr * 64 + r;
    const int bRow0 = wc * 64 + r;
    const int rx = r & 7;

#pragma unroll
    for (int p = 0; p < 4; ++p) {
        gload_lds16(gA[p], lA[p]);
        gload_lds16(gB[p], lB[p]);
    }

    for (int kc = 0; kc < D / BK; ++kc) {
        __syncthreads();
        short8 af[2][4], bf[2][4];
#pragma unroll
        for (int tt = 0; tt < 2; ++tt)
#pragma unroll
            for (int ti = 0; ti < 4; ++ti) {
                af[tt][ti] = *(const short8*)(Asm +
                    ((aRow0 + ti * 16) * 8 + ((tt * 4 + q) ^ rx)) * 8);
                bf[tt][ti] = *(const short8*)(Bsm +
                    ((bRow0 + ti * 16) * 8 + ((tt * 4 + q) ^ rx)) * 8);
            }
        __syncthreads();
        if (kc < D / BK - 1) {
            const int o = (kc + 1) * BK;
#pragma unroll
            for (int p = 0; p < 4; ++p) {
                gload_lds16(gA[p] + o, lA[p]);
                gload_lds16(gB[p] + o, lB[p]);
            }
        }
#pragma unroll
        for (int tt = 0; tt < 2; ++tt)
#pragma unroll
            for (int ti = 0; ti < 4; ++ti)
#pragma unroll
                for (int tj = 0; tj < 4; ++tj)
                    acc[ti][tj] = __builtin_amdgcn_mfma_f32_16x16x32_bf16(
                        af[tt][ti], bf[tt][tj], acc[ti][tj], 0, 0, 0);
    }

    // ---- A-side strip maxima: rows i0.., strip tjb*2 + wc ----
    {
        float rmax[16];
#pragma unroll
        for (int ti = 0; ti < 4; ++ti)
#pragma unroll
            for (int reg = 0; reg < 4; ++reg) {
                const float m0 = fmaxf(acc[ti][0][reg], acc[ti][1][reg]);
                const float m1 = fmaxf(acc[ti][2][reg], acc[ti][3][reg]);
                rmax[ti * 4 + reg] = fmaxf(m0, m1);
            }
#pragma unroll
        for (int k = 0; k < 16; ++k)
#pragma unroll
            for (int m = 1; m < 16; m <<= 1)
                rmax[k] = fmaxf(rmax[k], __shfl_xor(rmax[k], m, 64));
        if (r == 0) {
            const int strip = tjb * 2 + wc;
#pragma unroll
            for (int ti = 0; ti < 4; ++ti)
#pragma unroll
                for (int reg = 0; reg < 4; ++reg)
                    rowmaxG[(size_t)(i0 + wr * 64 + ti * 16 + q * 4 + reg) * NSTRIP +
                            strip] = f2b(rmax[ti * 4 + reg]);
        }
    }

    // ---- B-side strip maxima (mirror rows): rows j0.., strip tib*2 + wr --
    if (tib != tjb) {
        float cmax[4];
#pragma unroll
        for (int tj = 0; tj < 4; ++tj) {
            float m = -1e30f;
#pragma unroll
            for (int ti = 0; ti < 4; ++ti)
#pragma unroll
                for (int reg = 0; reg < 4; ++reg) m = fmaxf(m, acc[ti][tj][reg]);
            m = fmaxf(m, __shfl_xor(m, 16, 64));
            m = fmaxf(m, __shfl_xor(m, 32, 64));
            cmax[tj] = m;
        }
        if (q == 0) {
#pragma unroll
            for (int tj = 0; tj < 4; ++tj)
                rowmaxG[(size_t)(j0 + wc * 64 + tj * 16 + r) * NSTRIP + tib * 2 + wr] =
                    f2b(cmax[tj]);
        }
    }

    // ---- epilogue: LDS restage -> coalesced bf16 C writes (direct only) --
    __syncthreads();
    unsigned short* Cs = smem;
#pragma unroll
    for (int ti = 0; ti < 4; ++ti)
#pragma unroll
        for (int tj = 0; tj < 4; ++tj)
#pragma unroll
            for (int reg = 0; reg < 4; ++reg) {
                const int rowl = wr * 64 + ti * 16 + q * 4 + reg;
                const int coll = wc * 64 + tj * 16 + r;
                Cs[rowl * CPITCH + (coll ^ ((rowl & 7) << 3))] = f2b(acc[ti][tj][reg]);
            }
    __syncthreads();
#pragma unroll
    for (int p = 0; p < 8; ++p) {
        const int id = p * 256 + tid;
        const int rw = id >> 4;
        const int c = id & 15;
        const int cc = c ^ (rw & 7);
        const int4 v = *(const int4*)&Cs[rw * CPITCH + cc * 8];
        *(int4*)&Cout[(size_t)(i0 + rw) * N + j0 + c * 8] = v;
    }
    // (mirror tile write deleted — scanfin reads the transposed locations)
}

// ---------------- Kernel 3: bf16-direct top-5 + softmax + out ------------
// R10-proven: direct strips read coalesced; left-of-diagonal strips read
// transposed locations C[col][row]. Selection/softmax R7-proven.
__global__ __launch_bounds__(256) void scanfin_kernel(const unsigned short* __restrict__ C,
                                                      const unsigned short* __restrict__ rowmaxG,
                                                      float* __restrict__ out) {
    __shared__ int acnt[4];
    __shared__ int alist[4][NSTRIP];
    __shared__ int scnt[4];
    __shared__ unsigned int sci[4][CCAP];  // packed (sortable-bf16<<13 | 8191-col)
    const int tid = threadIdx.x;
    const int w = tid >> 6;
    const int lane = tid & 63;
    const int row = (int)blockIdx.x * 4 + w;
    const unsigned short* cr = C + (size_t)row * N;
    if (lane == 0) { acnt[w] = 0; scnt[w] = 0; }

    const ushort2 su = *(const ushort2*)(rowmaxG + (size_t)row * NSTRIP + lane * 2);
    const float s0v = b2f(su.x), s1v = b2f(su.y);

    // 5th-largest strip max via knockout (proven)
    float a = s0v, b = s1v;
    float m5 = -1e30f;
#pragma unroll
    for (int s = 0; s < 5; ++s) {
        float mx = fmaxf(a, b);
#pragma unroll
        for (int m = 32; m > 0; m >>= 1) mx = fmaxf(mx, __shfl_xor(mx, m, 64));
        m5 = mx;
        const unsigned long long msk = __ballot(a == mx || b == mx);
        const int first = __ffsll(msk) - 1;
        if (lane == first) {
            if (a == mx) a = -1e30f;
            else b = -1e30f;
        }
    }
    const float thr = m5;

    if (s0v >= thr) { const int p = atomicAdd(&acnt[w], 1); alist[w][p] = lane * 2; }
    if (s1v >= thr) { const int p = atomicAdd(&acnt[w], 1); alist[w][p] = lane * 2 + 1; }
    const int na = acnt[w];

    // gather candidates from qualifying strips; one strip per round.
    const int rowtile = row >> 7;
    for (int g = 0; g < na; ++g) {
        const int s = alist[w][g];
        const int col = s * 64 + lane;
        unsigned short uv;
        if ((s >> 1) >= rowtile) {
            uv = cr[col];
        } else {
            uv = C[(size_t)col * N + row];
        }
        const float v = b2f(uv);
        if (v >= thr) {
            const int p = atomicAdd(&scnt[w], 1);
            if (p < CCAP) sci[w][p] = packvi(uv, col);
        }
    }
    int nc = scnt[w];
    if (nc > CCAP) nc = CCAP;

    // uniform serial top-5 over packed keys (distinct; val desc, idx asc)
    unsigned int t5[5] = {0u, 0u, 0u, 0u, 0u};
    for (int c = 0; c < nc; ++c) {
        const unsigned int k = sci[w][c];
        if (k > t5[4]) {
            const bool b0 = k > t5[0];
            const bool b1 = k > t5[1];
            const bool b2 = k > t5[2];
            const bool b3 = k > t5[3];
            t5[4] = b3 ? t5[3] : k;
            t5[3] = b2 ? t5[2] : (b3 ? k : t5[3]);
            t5[2] = b1 ? t5[1] : (b2 ? k : t5[2]);
            t5[1] = b0 ? t5[0] : (b1 ? k : t5[1]);
            t5[0] = b0 ? k : t5[0];
        }
    }

    // write 5 entries (out pre-zeroed by harness memset)
    if (lane == 0) {
        const float vmax = upackval(t5[0]);
        float e[KSEL];
        int ix[KSEL];
        float sum = 0.f;
#pragma unroll
        for (int s = 0; s < KSEL; ++s) {
            const bool valid = (t5[s] != 0u);
            e[s] = valid ? expf((upackval(t5[s]) - vmax) * TEMP_INV) : 0.f;
            ix[s] = valid ? (8191 - (int)(t5[s] & 8191u)) : -1;
            sum += e[s];
        }
        const float invs = 1.0f / sum;
#pragma unroll
        for (int s = 0; s < KSEL; ++s) {
            if (ix[s] >= 0) out[(size_t)row * N + ix[s]] = e[s] * invs;
        }
    }
}

extern "C" void kernel_launch(void* const* d_in, const int* in_sizes, int n_in,
                              void* d_out, int out_size, void* d_ws, size_t ws_size,
                              hipStream_t stream) {
    const float* X = (const float*)d_in[0];
    float* out = (float*)d_out;
    // ws (1 GiB): Xb bf16 [8 MB] | rowmax bf16 [2 MB] | C bf16 [128 MB @ +16 MB]
    unsigned short* Xb = (unsigned short*)d_ws;
    unsigned short* rowmaxG = (unsigned short*)(Xb + (size_t)N * D);
    unsigned short* C = (unsigned short*)((char*)d_ws + (16u << 20));

    hipLaunchKernelGGL(prep_kernel, dim3(N), dim3(64), 0, stream, X, Xb);
    hipLaunchKernelGGL(gemm_kernel, dim3(NBLK), dim3(256), 0, stream, Xb, C, rowmaxG);
    hipLaunchKernelGGL(scanfin_kernel, dim3(N / 4), dim3(256), 0, stream, C, rowmaxG, out);
}

// Round 14
// 330.734 us; speedup vs baseline: 1.2175x; 1.0205x over previous
//
#include <hip/hip_runtime.h>
#include <math.h>

#define N 8192
#define D 512
#define KSEL 5
#define TEMP_INV 10.0f
#define CCAP 64
#define BK 64
#define CPITCH 136  // epilogue C-stage pitch in shorts (R5-proven)
#define NSTRIP 128  // 64-col strips per row
#define NTILE 64
#define NBLK (NTILE * (NTILE + 1) / 2)  // 2080 upper-triangle tiles (= 8*260)

using short8 = __attribute__((ext_vector_type(8))) short;
using floatx4 = __attribute__((ext_vector_type(4))) float;

__device__ inline unsigned short f2b(float f) {  // fp32 -> bf16 RNE (monotone)
    unsigned int u = __float_as_uint(f);
    unsigned int r = (u + 0x7FFFu + ((u >> 16) & 1u)) >> 16;
    return (unsigned short)r;
}
__device__ inline float b2f(unsigned short u) {
    return __uint_as_float(((unsigned int)u) << 16);
}

// pack (bf16 value, col) into one sortable u32: val desc, then idx asc.
// high 16 = bf16 mapped monotone-to-unsigned, low 13 = 8191-col.
__device__ inline unsigned int packvi(unsigned short b, int col) {
    const unsigned short s =
        (b & 0x8000) ? (unsigned short)(~b) : (unsigned short)(b | 0x8000);
    return ((unsigned int)s << 13) | (unsigned int)(8191 - col);
}
__device__ inline float upackval(unsigned int key) {
    const unsigned short s = (unsigned short)(key >> 13);
    const unsigned short b =
        (s & 0x8000) ? (unsigned short)(s & 0x7FFF) : (unsigned short)(~s);
    return b2f(b);
}

__device__ inline void gload_lds16(const unsigned short* g, unsigned short* l) {
    __builtin_amdgcn_global_load_lds((__attribute__((address_space(1))) void*)g,
                                     (__attribute__((address_space(3))) void*)l, 16, 0, 0);
}

// ---------------- Kernel 1: norms + bf16 normalized rows -----------------
__global__ __launch_bounds__(64) void prep_kernel(const float* __restrict__ X,
                                                  unsigned short* __restrict__ Xb) {
    const int row = blockIdx.x;
    const int t = threadIdx.x;
    const float4* xr = (const float4*)(X + (size_t)row * D);
    const float4 a = xr[t];
    const float4 b = xr[t + 64];
    float ss = a.x * a.x + a.y * a.y + a.z * a.z + a.w * a.w +
               b.x * b.x + b.y * b.y + b.z * b.z + b.w * b.w;
#pragma unroll
    for (int off = 32; off > 0; off >>= 1) ss += __shfl_xor(ss, off, 64);
    const float iv = 1.0f / fmaxf(sqrtf(ss), 1e-12f);
    ushort4 ua, ub;
    ua.x = f2b(a.x * iv); ua.y = f2b(a.y * iv); ua.z = f2b(a.z * iv); ua.w = f2b(a.w * iv);
    ub.x = f2b(b.x * iv); ub.y = f2b(b.y * iv); ub.z = f2b(b.z * iv); ub.w = f2b(b.w * iv);
    ((ushort4*)(Xb + (size_t)row * D))[t] = ua;
    ((ushort4*)(Xb + (size_t)row * D))[t + 64] = ub;
}

// ---------------- Kernel 2: symmetric bf16 MFMA GEMM ---------------------
// R13 body. R14: occupancy push — gemm is LDS+latency bound at 12 waves/CU
// (VGPR-capped ~150; LDS 34.8 KB would allow 4 blocks/CU = 16 waves).
// (1) 64-bit gA/gB pointer arrays (16 VGPR) -> 32-bit element offsets from
// the SGPR-uniform Xb base (8 VGPR, saddr+voffset form);
// (2) __launch_bounds__(256, 4) directs the allocator to <=128 VGPR.
__global__ __launch_bounds__(256, 4) void gemm_kernel(const unsigned short* __restrict__ Xb,
                                                      unsigned short* __restrict__ Cout,
                                                      unsigned short* __restrict__ rowmaxG) {
    __shared__ unsigned short smem[128 * CPITCH];  // 34.8 KB (A|B 32 KB, then Cs)
    unsigned short* Asm = smem;
    unsigned short* Bsm = smem + 8192;
    const int tid = threadIdx.x;
    const int w = tid >> 6;
    const int lane = tid & 63;
    const int wr = w >> 1, wc = w & 1;

    // XCD swizzle (R13-neutral, harmless): same-XCD blocks get consecutive tiles
    const int traw = (int)blockIdx.x;
    const int t = (traw & 7) * (NBLK / 8) + (traw >> 3);

    // decode upper-triangle pair: off(ti) = ti*(129-ti)/2
    int tib = (int)((129.0 - sqrt(129.0 * 129.0 - 8.0 * (double)t)) * 0.5);
    while ((tib + 1) * (129 - (tib + 1)) / 2 <= t) ++tib;
    while (tib * (129 - tib) / 2 > t) --tib;
    const int tjb = tib + (t - tib * (129 - tib) / 2);
    const int i0 = tib * 128, j0 = tjb * 128;

    floatx4 acc[4][4];
#pragma unroll
    for (int ti = 0; ti < 4; ++ti)
#pragma unroll
        for (int tj = 0; tj < 4; ++tj) acc[ti][tj] = (floatx4){0.f, 0.f, 0.f, 0.f};

    // 32-bit element offsets (shorts) from uniform Xb base; lA/lB LDS ptrs
    unsigned int oA[4], oB[4];
    unsigned short* lA[4];
    unsigned short* lB[4];
#pragma unroll
    for (int p = 0; p < 4; ++p) {
        const int slot = p * 256 + tid;
        const int row = slot >> 3;
        const int kq = (slot & 7) ^ (row & 7);
        oA[p] = (unsigned int)(i0 + row) * D + kq * 8;
        oB[p] = (unsigned int)(j0 + row) * D + kq * 8;
        lA[p] = Asm + slot * 8;
        lB[p] = Bsm + slot * 8;
    }

    const int r = lane & 15;
    const int q = lane >> 4;
    const int aRow0 = wr * 64 + r;
    const int bRow0 = wc * 64 + r;
    const int rx = r & 7;

#pragma unroll
    for (int p = 0; p < 4; ++p) {
        gload_lds16(Xb + oA[p], lA[p]);
        gload_lds16(Xb + oB[p], lB[p]);
    }

    for (int kc = 0; kc < D / BK; ++kc) {
        __syncthreads();
        short8 af[2][4], bf[2][4];
#pragma unroll
        for (int tt = 0; tt < 2; ++tt)
#pragma unroll
            for (int ti = 0; ti < 4; ++ti) {
                af[tt][ti] = *(const short8*)(Asm +
                    ((aRow0 + ti * 16) * 8 + ((tt * 4 + q) ^ rx)) * 8);
                bf[tt][ti] = *(const short8*)(Bsm +
                    ((bRow0 + ti * 16) * 8 + ((tt * 4 + q) ^ rx)) * 8);
            }
        __syncthreads();
        if (kc < D / BK - 1) {
            const unsigned int o = (unsigned int)(kc + 1) * BK;
#pragma unroll
            for (int p = 0; p < 4; ++p) {
                gload_lds16(Xb + oA[p] + o, lA[p]);
                gload_lds16(Xb + oB[p] + o, lB[p]);
            }
        }
#pragma unroll
        for (int tt = 0; tt < 2; ++tt)
#pragma unroll
            for (int ti = 0; ti < 4; ++ti)
#pragma unroll
                for (int tj = 0; tj < 4; ++tj)
                    acc[ti][tj] = __builtin_amdgcn_mfma_f32_16x16x32_bf16(
                        af[tt][ti], bf[tt][tj], acc[ti][tj], 0, 0, 0);
    }

    // ---- A-side strip maxima: rows i0.., strip tjb*2 + wc ----
    {
        float rmax[16];
#pragma unroll
        for (int ti = 0; ti < 4; ++ti)
#pragma unroll
            for (int reg = 0; reg < 4; ++reg) {
                const float m0 = fmaxf(acc[ti][0][reg], acc[ti][1][reg]);
                const float m1 = fmaxf(acc[ti][2][reg], acc[ti][3][reg]);
                rmax[ti * 4 + reg] = fmaxf(m0, m1);
            }
#pragma unroll
        for (int k = 0; k < 16; ++k)
#pragma unroll
            for (int m = 1; m < 16; m <<= 1)
                rmax[k] = fmaxf(rmax[k], __shfl_xor(rmax[k], m, 64));
        if (r == 0) {
            const int strip = tjb * 2 + wc;
#pragma unroll
            for (int ti = 0; ti < 4; ++ti)
#pragma unroll
                for (int reg = 0; reg < 4; ++reg)
                    rowmaxG[(size_t)(i0 + wr * 64 + ti * 16 + q * 4 + reg) * NSTRIP +
                            strip] = f2b(rmax[ti * 4 + reg]);
        }
    }

    // ---- B-side strip maxima (mirror rows): rows j0.., strip tib*2 + wr --
    if (tib != tjb) {
        float cmax[4];
#pragma unroll
        for (int tj = 0; tj < 4; ++tj) {
            float m = -1e30f;
#pragma unroll
            for (int ti = 0; ti < 4; ++ti)
#pragma unroll
                for (int reg = 0; reg < 4; ++reg) m = fmaxf(m, acc[ti][tj][reg]);
            m = fmaxf(m, __shfl_xor(m, 16, 64));
            m = fmaxf(m, __shfl_xor(m, 32, 64));
            cmax[tj] = m;
        }
        if (q == 0) {
#pragma unroll
            for (int tj = 0; tj < 4; ++tj)
                rowmaxG[(size_t)(j0 + wc * 64 + tj * 16 + r) * NSTRIP + tib * 2 + wr] =
                    f2b(cmax[tj]);
        }
    }

    // ---- epilogue: LDS restage -> coalesced bf16 C writes (direct only) --
    __syncthreads();
    unsigned short* Cs = smem;
#pragma unroll
    for (int ti = 0; ti < 4; ++ti)
#pragma unroll
        for (int tj = 0; tj < 4; ++tj)
#pragma unroll
            for (int reg = 0; reg < 4; ++reg) {
                const int rowl = wr * 64 + ti * 16 + q * 4 + reg;
                const int coll = wc * 64 + tj * 16 + r;
                Cs[rowl * CPITCH + (coll ^ ((rowl & 7) << 3))] = f2b(acc[ti][tj][reg]);
            }
    __syncthreads();
#pragma unroll
    for (int p = 0; p < 8; ++p) {
        const int id = p * 256 + tid;
        const int rw = id >> 4;
        const int c = id & 15;
        const int cc = c ^ (rw & 7);
        const int4 v = *(const int4*)&Cs[rw * CPITCH + cc * 8];
        *(int4*)&Cout[(size_t)(i0 + rw) * N + j0 + c * 8] = v;
    }
    // (mirror tile write deleted — scanfin reads the transposed locations)
}

// ---------------- Kernel 3: bf16-direct top-5 + softmax + out ------------
// R10-proven: direct strips read coalesced; left-of-diagonal strips read
// transposed locations C[col][row]. Selection/softmax R7-proven.
__global__ __launch_bounds__(256) void scanfin_kernel(const unsigned short* __restrict__ C,
                                                      const unsigned short* __restrict__ rowmaxG,
                                                      float* __restrict__ out) {
    __shared__ int acnt[4];
    __shared__ int alist[4][NSTRIP];
    __shared__ int scnt[4];
    __shared__ unsigned int sci[4][CCAP];  // packed (sortable-bf16<<13 | 8191-col)
    const int tid = threadIdx.x;
    const int w = tid >> 6;
    const int lane = tid & 63;
    const int row = (int)blockIdx.x * 4 + w;
    const unsigned short* cr = C + (size_t)row * N;
    if (lane == 0) { acnt[w] = 0; scnt[w] = 0; }

    const ushort2 su = *(const ushort2*)(rowmaxG + (size_t)row * NSTRIP + lane * 2);
    const float s0v = b2f(su.x), s1v = b2f(su.y);

    // 5th-largest strip max via knockout (proven)
    float a = s0v, b = s1v;
    float m5 = -1e30f;
#pragma unroll
    for (int s = 0; s < 5; ++s) {
        float mx = fmaxf(a, b);
#pragma unroll
        for (int m = 32; m > 0; m >>= 1) mx = fmaxf(mx, __shfl_xor(mx, m, 64));
        m5 = mx;
        const unsigned long long msk = __ballot(a == mx || b == mx);
        const int first = __ffsll(msk) - 1;
        if (lane == first) {
            if (a == mx) a = -1e30f;
            else b = -1e30f;
        }
    }
    const float thr = m5;

    if (s0v >= thr) { const int p = atomicAdd(&acnt[w], 1); alist[w][p] = lane * 2; }
    if (s1v >= thr) { const int p = atomicAdd(&acnt[w], 1); alist[w][p] = lane * 2 + 1; }
    const int na = acnt[w];

    // gather candidates from qualifying strips; one strip per round.
    const int rowtile = row >> 7;
    for (int g = 0; g < na; ++g) {
        const int s = alist[w][g];
        const int col = s * 64 + lane;
        unsigned short uv;
        if ((s >> 1) >= rowtile) {
            uv = cr[col];
        } else {
            uv = C[(size_t)col * N + row];
        }
        const float v = b2f(uv);
        if (v >= thr) {
            const int p = atomicAdd(&scnt[w], 1);
            if (p < CCAP) sci[w][p] = packvi(uv, col);
        }
    }
    int nc = scnt[w];
    if (nc > CCAP) nc = CCAP;

    // uniform serial top-5 over packed keys (distinct; val desc, idx asc)
    unsigned int t5[5] = {0u, 0u, 0u, 0u, 0u};
    for (int c = 0; c < nc; ++c) {
        const unsigned int k = sci[w][c];
        if (k > t5[4]) {
            const bool b0 = k > t5[0];
            const bool b1 = k > t5[1];
            const bool b2 = k > t5[2];
            const bool b3 = k > t5[3];
            t5[4] = b3 ? t5[3] : k;
            t5[3] = b2 ? t5[2] : (b3 ? k : t5[3]);
            t5[2] = b1 ? t5[1] : (b2 ? k : t5[2]);
            t5[1] = b0 ? t5[0] : (b1 ? k : t5[1]);
            t5[0] = b0 ? k : t5[0];
        }
    }

    // write 5 entries (out pre-zeroed by harness memset)
    if (lane == 0) {
        const float vmax = upackval(t5[0]);
        float e[KSEL];
        int ix[KSEL];
        float sum = 0.f;
#pragma unroll
        for (int s = 0; s < KSEL; ++s) {
            const bool valid = (t5[s] != 0u);
            e[s] = valid ? expf((upackval(t5[s]) - vmax) * TEMP_INV) : 0.f;
            ix[s] = valid ? (8191 - (int)(t5[s] & 8191u)) : -1;
            sum += e[s];
        }
        const float invs = 1.0f / sum;
#pragma unroll
        for (int s = 0; s < KSEL; ++s) {
            if (ix[s] >= 0) out[(size_t)row * N + ix[s]] = e[s] * invs;
        }
    }
}

extern "C" void kernel_launch(void* const* d_in, const int* in_sizes, int n_in,
                              void* d_out, int out_size, void* d_ws, size_t ws_size,
                              hipStream_t stream) {
    const float* X = (const float*)d_in[0];
    float* out = (float*)d_out;
    // ws (1 GiB): Xb bf16 [8 MB] | rowmax bf16 [2 MB] | C bf16 [128 MB @ +16 MB]
    unsigned short* Xb = (unsigned short*)d_ws;
    unsigned short* rowmaxG = (unsigned short*)(Xb + (size_t)N * D);
    unsigned short* C = (unsigned short*)((char*)d_ws + (16u << 20));

    hipLaunchKernelGGL(prep_kernel, dim3(N), dim3(64), 0, stream, X, Xb);
    hipLaunchKernelGGL(gemm_kernel, dim3(NBLK), dim3(256), 0, stream, Xb, C, rowmaxG);
    hipLaunchKernelGGL(scanfin_kernel, dim3(N / 4), dim3(256), 0, stream, C, rowmaxG, out);
}